// Round 1
// baseline (5574.062 us; speedup 1.0000x reference)
//
#include <hip/hip_runtime.h>
#include <cstdint>
#include <cstddef>

#define B_   64
#define S_   49
#define T_   32
#define D_   512
#define V_   32000
#define G3   1536
#define NCAT 2560

typedef short s16x8 __attribute__((ext_vector_type(8)));
typedef float v4f   __attribute__((ext_vector_type(4)));

__device__ __forceinline__ float sigm(float x) { return 1.f / (1.f + __expf(-x)); }

__device__ __forceinline__ unsigned short f2bf(float f) {
  unsigned u = __float_as_uint(f);
  return (unsigned short)((u + 0x7FFFu + ((u >> 16) & 1u)) >> 16);
}

// ---------------- fp32 -> bf16 conversion (8 elems/thread) ----------------
__global__ __launch_bounds__(256) void k_cvt(const float* __restrict__ in,
                                             unsigned short* __restrict__ out) {
  int i = (blockIdx.x * 256 + threadIdx.x) * 8;
  float4 a = *(const float4*)(in + i);
  float4 b = *(const float4*)(in + i + 4);
  s16x8 o;
  o[0] = (short)f2bf(a.x); o[1] = (short)f2bf(a.y);
  o[2] = (short)f2bf(a.z); o[3] = (short)f2bf(a.w);
  o[4] = (short)f2bf(b.x); o[5] = (short)f2bf(b.y);
  o[6] = (short)f2bf(b.z); o[7] = (short)f2bf(b.w);
  *(s16x8*)(out + i) = o;
}

// ---------------- embedding gather + active mask ----------------
// x_embed row m = t*64 + b  (matches gi_embed rows used by S3)
// actmask indexed by b*32+t (matches output GEMM rows)
__global__ __launch_bounds__(128) void k_embed(const float* __restrict__ emb,
    const int* __restrict__ seq, const int* __restrict__ length,
    float* __restrict__ x_embed, float* __restrict__ actmask) {
  int m = blockIdx.x;
  int t = m >> 6, b = m & 63;
  int idx = seq[b * T_ + t];
  const float4* src = (const float4*)(emb + (size_t)idx * D_);
  float4* dst = (float4*)(x_embed + (size_t)m * D_);
  dst[threadIdx.x] = src[threadIdx.x];
  if (threadIdx.x == 0) actmask[b * T_ + t] = (t < length[b]) ? 1.f : 0.f;
}

// ---------------- feats mean + scope init ----------------
__global__ __launch_bounds__(256) void k_hmean(const float* __restrict__ feats,
    float* __restrict__ hmean, float* __restrict__ scope) {
  int b = blockIdx.x, tid = threadIdx.x;
  for (int e = tid; e < D_; e += 256) {
    float s = 0.f;
    for (int si = 0; si < S_; ++si) s += feats[((size_t)b * S_ + si) * D_ + e];
    hmean[b * D_ + e] = s * (1.f / 49.f);
  }
  if (tid < S_) scope[b * S_ + tid] = 1.f;
}

// ---------------- generic fp32 GEMM: C[M,N] = X[M,K] @ W[N,ldw].T + bias ----------------
// tiles 64x64, BK=32, 256 threads, 4x4 per thread. M,N multiples of 64; K mult of 32.
__global__ __launch_bounds__(256) void k_gemm_f32(
    float* __restrict__ C, const float* __restrict__ X, const float* __restrict__ W,
    const float* __restrict__ bias, int N, int K, int ldw) {
  __shared__ __align__(16) float XsT[32][68];
  __shared__ __align__(16) float WsT[32][68];
  const int nbase = blockIdx.x * 64, mbase = blockIdx.y * 64;
  const int tid = threadIdx.x;
  const int lr = tid >> 2;          // 0..63 load row
  const int lk = (tid & 3) * 8;     // 0,8,16,24 k offset
  const int ty = tid >> 4, tx = tid & 15;
  float acc[4][4] = {};
  for (int k0 = 0; k0 < K; k0 += 32) {
    {
      const float* xs = X + (size_t)(mbase + lr) * K + k0 + lk;
      const float* wsrc = W + (size_t)(nbase + lr) * ldw + k0 + lk;
      float4 x0 = *(const float4*)xs, x1 = *(const float4*)(xs + 4);
      float4 w0 = *(const float4*)wsrc, w1 = *(const float4*)(wsrc + 4);
      XsT[lk + 0][lr] = x0.x; XsT[lk + 1][lr] = x0.y; XsT[lk + 2][lr] = x0.z; XsT[lk + 3][lr] = x0.w;
      XsT[lk + 4][lr] = x1.x; XsT[lk + 5][lr] = x1.y; XsT[lk + 6][lr] = x1.z; XsT[lk + 7][lr] = x1.w;
      WsT[lk + 0][lr] = w0.x; WsT[lk + 1][lr] = w0.y; WsT[lk + 2][lr] = w0.z; WsT[lk + 3][lr] = w0.w;
      WsT[lk + 4][lr] = w1.x; WsT[lk + 5][lr] = w1.y; WsT[lk + 6][lr] = w1.z; WsT[lk + 7][lr] = w1.w;
    }
    __syncthreads();
    #pragma unroll
    for (int kk = 0; kk < 32; ++kk) {
      float4 a4 = *(const float4*)&XsT[kk][ty * 4];
      float4 w4 = *(const float4*)&WsT[kk][tx * 4];
      float av[4] = {a4.x, a4.y, a4.z, a4.w};
      float wv[4] = {w4.x, w4.y, w4.z, w4.w};
      #pragma unroll
      for (int i = 0; i < 4; ++i)
        #pragma unroll
        for (int j = 0; j < 4; ++j)
          acc[i][j] = fmaf(av[i], wv[j], acc[i][j]);
    }
    __syncthreads();
  }
  #pragma unroll
  for (int i = 0; i < 4; ++i) {
    int m = mbase + ty * 4 + i;
    int n = nbase + tx * 4;
    float4 o;
    o.x = acc[i][0] + bias[n + 0];
    o.y = acc[i][1] + bias[n + 1];
    o.z = acc[i][2] + bias[n + 2];
    o.w = acc[i][3] + bias[n + 3];
    *(float4*)&C[(size_t)m * N + n] = o;
  }
}

// ---------------- S1: Yp[ks][b][0:2560] = h @ [W_hh|W_da|W_beta].T (K-slice ks), bias on ks==0
__global__ __launch_bounds__(256) void k_S1(const float* __restrict__ h,
    const float* __restrict__ Whh, const float* __restrict__ bhh,
    const float* __restrict__ Wda, const float* __restrict__ bda,
    const float* __restrict__ Wbe, const float* __restrict__ bbe,
    float* __restrict__ Yp) {
  __shared__ __align__(16) float hs[64 * 129];
  const int tid = threadIdx.x;
  const int nbase = blockIdx.x * 32;
  const int ks = blockIdx.y;
  const int kb = ks * 128;
  {
    int lrow = tid >> 2, lkc = (tid & 3) * 32;
    const float* src = h + lrow * 512 + kb + lkc;
    float* dst = hs + lrow * 129 + lkc;
    #pragma unroll
    for (int i = 0; i < 32; i += 4) {
      float4 v = *(const float4*)(src + i);
      dst[i] = v.x; dst[i + 1] = v.y; dst[i + 2] = v.z; dst[i + 3] = v.w;
    }
  }
  __syncthreads();
  int b = tid & 63, ng = tid >> 6;
  int n0 = nbase + ng * 8;
  const float* W; const float* bi; int nl;
  if (n0 < 1536)      { W = Whh; bi = bhh; nl = n0; }
  else if (n0 < 2048) { W = Wda; bi = bda; nl = n0 - 1536; }
  else                { W = Wbe; bi = bbe; nl = n0 - 2048; }
  const float* w0 = W + (size_t)nl * 512 + kb;
  float acc[8] = {};
  const float* xrow = hs + b * 129;
  for (int kk = 0; kk < 128; kk += 4) {
    float x0 = xrow[kk], x1 = xrow[kk + 1], x2 = xrow[kk + 2], x3 = xrow[kk + 3];
    #pragma unroll
    for (int jj = 0; jj < 8; ++jj) {
      float4 w = *(const float4*)(w0 + (size_t)jj * 512 + kk);
      acc[jj] = fmaf(x0, w.x, fmaf(x1, w.y, fmaf(x2, w.z, fmaf(x3, w.w, acc[jj]))));
    }
  }
  if (ks == 0) {
    #pragma unroll
    for (int jj = 0; jj < 8; ++jj) acc[jj] += bi[nl + jj];
  }
  float* yp = Yp + ((size_t)ks * 64 + b) * NCAT + n0;
  float4 o0 = {acc[0], acc[1], acc[2], acc[3]};
  float4 o1 = {acc[4], acc[5], acc[6], acc[7]};
  *(float4*)yp = o0; *(float4*)(yp + 4) = o1;
}

// ---------------- S2: attention + softmax + scope/alphas + awe + gate -> xg ----------------
__global__ __launch_bounds__(256) void k_S2(int t,
    const float* __restrict__ Yp, const float* __restrict__ att1,
    const float* __restrict__ feats, const float* __restrict__ W_fa,
    const float* __restrict__ b_fa, const int* __restrict__ length,
    float* __restrict__ scope, float* __restrict__ xg,
    float* __restrict__ alphas_out) {
  __shared__ float att2_s[512];
  __shared__ float gate_s[512];
  __shared__ float att_s[64];
  __shared__ float alpha_s[64];
  int b = blockIdx.x, tid = threadIdx.x;
  bool act = t < length[b];
  for (int a = tid; a < 512; a += 256) {
    float s1 = 0.f, s2 = 0.f;
    #pragma unroll
    for (int ks = 0; ks < 4; ++ks) {
      const float* y = Yp + ((size_t)ks * 64 + b) * NCAT;
      s1 += y[1536 + a];
      s2 += y[2048 + a];
    }
    att2_s[a] = s1;
    gate_s[a] = sigm(s2);
  }
  __syncthreads();
  int lane = tid & 63, wv = tid >> 6;
  for (int s = wv; s < S_; s += 4) {
    const float* arow = att1 + ((size_t)b * S_ + s) * D_;
    int a0 = lane * 8;
    float p = 0.f;
    #pragma unroll
    for (int j = 0; j < 8; ++j) {
      float v = arow[a0 + j] + att2_s[a0 + j];
      v = v > 0.f ? v : 0.f;
      p = fmaf(v, W_fa[a0 + j], p);
    }
    #pragma unroll
    for (int off = 32; off > 0; off >>= 1) p += __shfl_xor(p, off, 64);
    if (lane == 0) att_s[s] = p + b_fa[0];
  }
  __syncthreads();
  if (tid < 64) {
    float x = (tid < S_) ? att_s[tid] : -1e30f;
    float m = x;
    #pragma unroll
    for (int off = 32; off > 0; off >>= 1) m = fmaxf(m, __shfl_xor(m, off, 64));
    float e = (tid < S_) ? __expf(x - m) : 0.f;
    float su = e;
    #pragma unroll
    for (int off = 32; off > 0; off >>= 1) su += __shfl_xor(su, off, 64);
    if (tid < S_) alpha_s[tid] = e / su;
  }
  __syncthreads();
  if (tid < S_) {
    float old = scope[b * S_ + tid], al = alpha_s[tid];
    alphas_out[((size_t)b * T_ + t) * S_ + tid] = act ? old * al : 0.f;
    scope[b * S_ + tid] = act ? old * (1.f - al) : old;
  }
  for (int e = tid; e < D_; e += 256) {
    float aw = 0.f;
    for (int s = 0; s < S_; ++s)
      aw = fmaf(alpha_s[s], feats[((size_t)b * S_ + s) * D_ + e], aw);
    xg[b * D_ + e] = gate_s[e] * aw;
  }
}

// ---------------- S3: gi_awe matmul + GRU pointwise; updates h, stores h_new (bf16) ----------------
__global__ __launch_bounds__(256) void k_S3(int t,
    float* __restrict__ h, const float* __restrict__ xg,
    const float* __restrict__ Yp, const float* __restrict__ gi_embed,
    const float* __restrict__ W_ih, const int* __restrict__ length,
    unsigned short* __restrict__ Hbuf) {
  __shared__ __align__(16) float xs[64 * 129];
  int tid = threadIdx.x;
  int b = tid & 63, jg = tid >> 6;
  int j = blockIdx.x * 4 + jg;
  const float* Wr = W_ih + (size_t)j * 1024 + 512;
  const float* Wz = W_ih + (size_t)(512 + j) * 1024 + 512;
  const float* Wn = W_ih + (size_t)(1024 + j) * 1024 + 512;
  float accr = 0.f, accz = 0.f, accn = 0.f;
  int lrow = tid >> 2, lkc = (tid & 3) * 32;
  for (int c = 0; c < 4; ++c) {
    int kb = c * 128;
    {
      const float* src = xg + lrow * 512 + kb + lkc;
      float* dst = xs + lrow * 129 + lkc;
      #pragma unroll
      for (int i = 0; i < 32; i += 4) {
        float4 v = *(const float4*)(src + i);
        dst[i] = v.x; dst[i + 1] = v.y; dst[i + 2] = v.z; dst[i + 3] = v.w;
      }
    }
    __syncthreads();
    const float* xrow = xs + b * 129;
    for (int kk = 0; kk < 128; kk += 4) {
      float x0 = xrow[kk], x1 = xrow[kk + 1], x2 = xrow[kk + 2], x3 = xrow[kk + 3];
      float4 w;
      w = *(const float4*)(Wr + kb + kk);
      accr = fmaf(x0, w.x, fmaf(x1, w.y, fmaf(x2, w.z, fmaf(x3, w.w, accr))));
      w = *(const float4*)(Wz + kb + kk);
      accz = fmaf(x0, w.x, fmaf(x1, w.y, fmaf(x2, w.z, fmaf(x3, w.w, accz))));
      w = *(const float4*)(Wn + kb + kk);
      accn = fmaf(x0, w.x, fmaf(x1, w.y, fmaf(x2, w.z, fmaf(x3, w.w, accn))));
    }
    __syncthreads();
  }
  float ghr = 0.f, ghz = 0.f, ghn = 0.f;
  #pragma unroll
  for (int ks = 0; ks < 4; ++ks) {
    const float* y = Yp + ((size_t)ks * 64 + b) * NCAT;
    ghr += y[j]; ghz += y[512 + j]; ghn += y[1024 + j];
  }
  const float* gm = gi_embed + ((size_t)t * 64 + b) * G3;
  float r = sigm(accr + gm[j] + ghr);
  float z = sigm(accz + gm[512 + j] + ghz);
  float n = tanhf(accn + gm[1024 + j] + r * ghn);
  float hold = h[b * D_ + j];
  float hn = (1.f - z) * n + z * hold;
  bool act = t < length[b];
  h[b * D_ + j] = act ? hn : hold;
  Hbuf[((size_t)b * T_ + t) * D_ + j] = f2bf(hn);
}

// ---------------- Phase C: out[m][n] = actmask[m]*(Hbuf[m,:]@Wout[n,:] + b_out[n]) ----------------
// bf16 MFMA 16x16x32, 128x128 tile, 4 waves (2x2), 4x4 fragments/wave, BK=32
__global__ __launch_bounds__(256) void k_outgemm(
    const unsigned short* __restrict__ Hb, const unsigned short* __restrict__ Wb,
    const float* __restrict__ b_out, const float* __restrict__ actmask,
    float* __restrict__ out) {
  __shared__ __align__(16) unsigned short As[128 * 32];
  __shared__ __align__(16) unsigned short Bs[128 * 32];
  const int nb = blockIdx.x * 128, mb = blockIdx.y * 128;
  const int tid = threadIdx.x;
  const int l = tid & 63, w = tid >> 6;
  const int wr = w >> 1, wc = w & 1;
  const int lm = l & 15, lk8 = (l >> 4) * 8;
  v4f acc[4][4];
  #pragma unroll
  for (int mi = 0; mi < 4; ++mi)
    #pragma unroll
    for (int ni = 0; ni < 4; ++ni)
      acc[mi][ni] = (v4f){0.f, 0.f, 0.f, 0.f};

  for (int k0 = 0; k0 < 512; k0 += 32) {
    #pragma unroll
    for (int i = 0; i < 2; ++i) {
      int ch = i * 256 + tid;          // 0..511 16B-chunks
      int row = ch >> 2, c4 = ch & 3;
      *(int4*)&As[row * 32 + c4 * 8] =
          *(const int4*)&Hb[(size_t)(mb + row) * 512 + k0 + c4 * 8];
      *(int4*)&Bs[row * 32 + c4 * 8] =
          *(const int4*)&Wb[(size_t)(nb + row) * 512 + k0 + c4 * 8];
    }
    __syncthreads();
    s16x8 af[4], bf[4];
    #pragma unroll
    for (int mi = 0; mi < 4; ++mi)
      af[mi] = *(const s16x8*)&As[(wr * 64 + mi * 16 + lm) * 32 + lk8];
    #pragma unroll
    for (int ni = 0; ni < 4; ++ni)
      bf[ni] = *(const s16x8*)&Bs[(wc * 64 + ni * 16 + lm) * 32 + lk8];
    #pragma unroll
    for (int mi = 0; mi < 4; ++mi)
      #pragma unroll
      for (int ni = 0; ni < 4; ++ni)
        acc[mi][ni] = __builtin_amdgcn_mfma_f32_16x16x32_bf16(af[mi], bf[ni], acc[mi][ni], 0, 0, 0);
    __syncthreads();
  }
  #pragma unroll
  for (int ni = 0; ni < 4; ++ni) {
    int n = nb + wc * 64 + ni * 16 + lm;
    float bo = b_out[n];
    #pragma unroll
    for (int mi = 0; mi < 4; ++mi) {
      int m0 = mb + wr * 64 + mi * 16 + (l >> 4) * 4;
      #pragma unroll
      for (int r = 0; r < 4; ++r) {
        int m = m0 + r;
        out[(size_t)m * V_ + n] = actmask[m] * (acc[mi][ni][r] + bo);
      }
    }
  }
}

extern "C" void kernel_launch(void* const* d_in, const int* in_sizes, int n_in,
                              void* d_out, int out_size, void* d_ws, size_t ws_size,
                              hipStream_t stream) {
  const float* feats  = (const float*)d_in[0];
  const int*   seq    = (const int*)d_in[1];
  const int*   length = (const int*)d_in[2];
  const float* emb    = (const float*)d_in[3];
  const float* W_ih   = (const float*)d_in[4];
  const float* b_ih   = (const float*)d_in[5];
  const float* W_hh   = (const float*)d_in[6];
  const float* b_hh   = (const float*)d_in[7];
  const float* W_out  = (const float*)d_in[8];
  const float* b_out  = (const float*)d_in[9];
  const float* W_init = (const float*)d_in[10];
  const float* b_init = (const float*)d_in[11];
  const float* W_beta = (const float*)d_in[12];
  const float* b_beta = (const float*)d_in[13];
  const float* W_ea   = (const float*)d_in[14];
  const float* b_ea   = (const float*)d_in[15];
  const float* W_da   = (const float*)d_in[16];
  const float* b_da   = (const float*)d_in[17];
  const float* W_fa   = (const float*)d_in[18];
  const float* b_fa   = (const float*)d_in[19];

  float* out    = (float*)d_out;
  float* alphas = out + (size_t)B_ * T_ * V_;

  float* ws = (float*)d_ws;
  float* h        = ws; ws += B_ * D_;
  float* scope    = ws; ws += B_ * S_;
  float* hmean    = ws; ws += B_ * D_;
  float* xg       = ws; ws += B_ * D_;
  float* actmask  = ws; ws += B_ * T_;
  float* Yp       = ws; ws += 4 * B_ * NCAT;
  float* x_embed  = ws; ws += (size_t)B_ * T_ * D_;
  float* gi_embed = ws; ws += (size_t)B_ * T_ * G3;
  float* att1     = ws; ws += (size_t)B_ * S_ * D_;
  unsigned short* Hbuf  = (unsigned short*)ws;
  unsigned short* Woutb = Hbuf + (size_t)B_ * T_ * D_;

  // ---- Phase A: precompute (parallel) ----
  k_cvt<<<(V_ * D_) / 2048, 256, 0, stream>>>(W_out, Woutb);
  k_embed<<<B_ * T_, 128, 0, stream>>>(emb, seq, length, x_embed, actmask);
  k_hmean<<<B_, 256, 0, stream>>>(feats, hmean, scope);
  // h0 = hmean @ W_init.T + b_init
  k_gemm_f32<<<dim3(8, 1), 256, 0, stream>>>(h, hmean, W_init, b_init, 512, 512, 512);
  // att1 = feats @ W_ea.T + b_ea
  k_gemm_f32<<<dim3(8, 49), 256, 0, stream>>>(att1, feats, W_ea, b_ea, 512, 512, 512);
  // gi_embed = x_embed @ W_ih[:, :512].T + b_ih   (ldw = 1024)
  k_gemm_f32<<<dim3(24, 32), 256, 0, stream>>>(gi_embed, x_embed, W_ih, b_ih, 1536, 512, 1024);

  // ---- Phase B: recurrence ----
  for (int t = 0; t < T_; ++t) {
    k_S1<<<dim3(80, 4), 256, 0, stream>>>(h, W_hh, b_hh, W_da, b_da, W_beta, b_beta, Yp);
    k_S2<<<B_, 256, 0, stream>>>(t, Yp, att1, feats, W_fa, b_fa, length, scope, xg, alphas);
    k_S3<<<128, 256, 0, stream>>>(t, h, xg, Yp, gi_embed, W_ih, length, Hbuf);
  }

  // ---- Phase C: deferred output projection ----
  k_outgemm<<<dim3(250, 16), 256, 0, stream>>>(Hbuf, Woutb, b_out, actmask, out);
}

// Round 2
// 2241.916 us; speedup vs baseline: 2.4863x; 2.4863x over previous
//
#include <hip/hip_runtime.h>
#include <cstdint>
#include <cstddef>

#define B_   64
#define S_   49
#define T_   32
#define D_   512
#define V_   32000
#define G3   1536
#define NCAT 2560

typedef short s16x8 __attribute__((ext_vector_type(8)));
typedef float v4f   __attribute__((ext_vector_type(4)));

__device__ __forceinline__ float sigm(float x) { return 1.f / (1.f + __expf(-x)); }

__device__ __forceinline__ unsigned short f2bf(float f) {
  unsigned u = __float_as_uint(f);
  return (unsigned short)((u + 0x7FFFu + ((u >> 16) & 1u)) >> 16);
}

// ---------------- fp32 -> bf16 conversion (8 elems/thread) ----------------
__global__ __launch_bounds__(256) void k_cvt(const float* __restrict__ in,
                                             unsigned short* __restrict__ out) {
  int i = (blockIdx.x * 256 + threadIdx.x) * 8;
  float4 a = *(const float4*)(in + i);
  float4 b = *(const float4*)(in + i + 4);
  s16x8 o;
  o[0] = (short)f2bf(a.x); o[1] = (short)f2bf(a.y);
  o[2] = (short)f2bf(a.z); o[3] = (short)f2bf(a.w);
  o[4] = (short)f2bf(b.x); o[5] = (short)f2bf(b.y);
  o[6] = (short)f2bf(b.z); o[7] = (short)f2bf(b.w);
  *(s16x8*)(out + i) = o;
}

// ---------------- embedding gather + active mask ----------------
__global__ __launch_bounds__(128) void k_embed(const float* __restrict__ emb,
    const int* __restrict__ seq, const int* __restrict__ length,
    float* __restrict__ x_embed, float* __restrict__ actmask) {
  int m = blockIdx.x;
  int t = m >> 6, b = m & 63;
  int idx = seq[b * T_ + t];
  const float4* src = (const float4*)(emb + (size_t)idx * D_);
  float4* dst = (float4*)(x_embed + (size_t)m * D_);
  dst[threadIdx.x] = src[threadIdx.x];
  if (threadIdx.x == 0) actmask[b * T_ + t] = (t < length[b]) ? 1.f : 0.f;
}

// ---------------- feats mean + scope init ----------------
__global__ __launch_bounds__(256) void k_hmean(const float* __restrict__ feats,
    float* __restrict__ hmean, float* __restrict__ scope) {
  int b = blockIdx.x, tid = threadIdx.x;
  for (int e = tid; e < D_; e += 256) {
    float s = 0.f;
    for (int si = 0; si < S_; ++si) s += feats[((size_t)b * S_ + si) * D_ + e];
    hmean[b * D_ + e] = s * (1.f / 49.f);
  }
  if (tid < S_) scope[b * S_ + tid] = 1.f;
}

// ---------------- generic fp32 GEMM: C[M,N] = X[M,K] @ W[N,ldw].T + bias ----------------
__global__ __launch_bounds__(256) void k_gemm_f32(
    float* __restrict__ C, const float* __restrict__ X, const float* __restrict__ W,
    const float* __restrict__ bias, int N, int K, int ldw) {
  __shared__ __align__(16) float XsT[32][68];
  __shared__ __align__(16) float WsT[32][68];
  const int nbase = blockIdx.x * 64, mbase = blockIdx.y * 64;
  const int tid = threadIdx.x;
  const int lr = tid >> 2;
  const int lk = (tid & 3) * 8;
  const int ty = tid >> 4, tx = tid & 15;
  float acc[4][4] = {};
  for (int k0 = 0; k0 < K; k0 += 32) {
    {
      const float* xs = X + (size_t)(mbase + lr) * K + k0 + lk;
      const float* wsrc = W + (size_t)(nbase + lr) * ldw + k0 + lk;
      float4 x0 = *(const float4*)xs, x1 = *(const float4*)(xs + 4);
      float4 w0 = *(const float4*)wsrc, w1 = *(const float4*)(wsrc + 4);
      XsT[lk + 0][lr] = x0.x; XsT[lk + 1][lr] = x0.y; XsT[lk + 2][lr] = x0.z; XsT[lk + 3][lr] = x0.w;
      XsT[lk + 4][lr] = x1.x; XsT[lk + 5][lr] = x1.y; XsT[lk + 6][lr] = x1.z; XsT[lk + 7][lr] = x1.w;
      WsT[lk + 0][lr] = w0.x; WsT[lk + 1][lr] = w0.y; WsT[lk + 2][lr] = w0.z; WsT[lk + 3][lr] = w0.w;
      WsT[lk + 4][lr] = w1.x; WsT[lk + 5][lr] = w1.y; WsT[lk + 6][lr] = w1.z; WsT[lk + 7][lr] = w1.w;
    }
    __syncthreads();
    #pragma unroll
    for (int kk = 0; kk < 32; ++kk) {
      float4 a4 = *(const float4*)&XsT[kk][ty * 4];
      float4 w4 = *(const float4*)&WsT[kk][tx * 4];
      float av[4] = {a4.x, a4.y, a4.z, a4.w};
      float wv[4] = {w4.x, w4.y, w4.z, w4.w};
      #pragma unroll
      for (int i = 0; i < 4; ++i)
        #pragma unroll
        for (int j = 0; j < 4; ++j)
          acc[i][j] = fmaf(av[i], wv[j], acc[i][j]);
    }
    __syncthreads();
  }
  #pragma unroll
  for (int i = 0; i < 4; ++i) {
    int m = mbase + ty * 4 + i;
    int n = nbase + tx * 4;
    float4 o;
    o.x = acc[i][0] + bias[n + 0];
    o.y = acc[i][1] + bias[n + 1];
    o.z = acc[i][2] + bias[n + 2];
    o.w = acc[i][3] + bias[n + 3];
    *(float4*)&C[(size_t)m * N + n] = o;
  }
}

// ---------------- S1: Yp[ks][b][0:2560] = h @ [W_hh|W_da|W_beta].T (K-slice ks) ----------------
__global__ __launch_bounds__(256) void k_S1(const float* __restrict__ h,
    const float* __restrict__ Whh, const float* __restrict__ bhh,
    const float* __restrict__ Wda, const float* __restrict__ bda,
    const float* __restrict__ Wbe, const float* __restrict__ bbe,
    float* __restrict__ Yp) {
  __shared__ __align__(16) float hs[64 * 129];
  const int tid = threadIdx.x;
  const int nbase = blockIdx.x * 32;
  const int ks = blockIdx.y;
  const int kb = ks * 128;
  {
    int lrow = tid >> 2, lkc = (tid & 3) * 32;
    const float* src = h + lrow * 512 + kb + lkc;
    float* dst = hs + lrow * 129 + lkc;
    #pragma unroll
    for (int i = 0; i < 32; i += 4) {
      float4 v = *(const float4*)(src + i);
      dst[i] = v.x; dst[i + 1] = v.y; dst[i + 2] = v.z; dst[i + 3] = v.w;
    }
  }
  __syncthreads();
  int b = tid & 63, ng = tid >> 6;
  int n0 = nbase + ng * 8;
  const float* W; const float* bi; int nl;
  if (n0 < 1536)      { W = Whh; bi = bhh; nl = n0; }
  else if (n0 < 2048) { W = Wda; bi = bda; nl = n0 - 1536; }
  else                { W = Wbe; bi = bbe; nl = n0 - 2048; }
  const float* w0 = W + (size_t)nl * 512 + kb;
  float acc[8] = {};
  const float* xrow = hs + b * 129;
  #pragma unroll 2
  for (int kk = 0; kk < 128; kk += 4) {
    float x0 = xrow[kk], x1 = xrow[kk + 1], x2 = xrow[kk + 2], x3 = xrow[kk + 3];
    #pragma unroll
    for (int jj = 0; jj < 8; ++jj) {
      float4 w = *(const float4*)(w0 + (size_t)jj * 512 + kk);
      acc[jj] = fmaf(x0, w.x, fmaf(x1, w.y, fmaf(x2, w.z, fmaf(x3, w.w, acc[jj]))));
    }
  }
  if (ks == 0) {
    #pragma unroll
    for (int jj = 0; jj < 8; ++jj) acc[jj] += bi[nl + jj];
  }
  float* yp = Yp + ((size_t)ks * 64 + b) * NCAT + n0;
  float4 o0 = {acc[0], acc[1], acc[2], acc[3]};
  float4 o1 = {acc[4], acc[5], acc[6], acc[7]};
  *(float4*)yp = o0; *(float4*)(yp + 4) = o1;
}

// ---------------- S2: attention + softmax + scope/alphas + awe + gate -> xg ----------------
__global__ __launch_bounds__(256) void k_S2(int t,
    const float* __restrict__ Yp, const float* __restrict__ att1,
    const float* __restrict__ feats, const float* __restrict__ W_fa,
    const float* __restrict__ b_fa, const int* __restrict__ length,
    float* __restrict__ scope, float* __restrict__ xg,
    float* __restrict__ alphas_out) {
  __shared__ float att2_s[512];
  __shared__ float gate_s[512];
  __shared__ float att_s[64];
  __shared__ float alpha_s[64];
  int b = blockIdx.x, tid = threadIdx.x;
  bool act = t < length[b];
  for (int a = tid; a < 512; a += 256) {
    float s1 = 0.f, s2 = 0.f;
    #pragma unroll
    for (int ks = 0; ks < 4; ++ks) {
      const float* y = Yp + ((size_t)ks * 64 + b) * NCAT;
      s1 += y[1536 + a];
      s2 += y[2048 + a];
    }
    att2_s[a] = s1;
    gate_s[a] = sigm(s2);
  }
  __syncthreads();
  int lane = tid & 63, wv = tid >> 6;
  for (int s = wv; s < S_; s += 4) {
    const float* arow = att1 + ((size_t)b * S_ + s) * D_;
    int a0 = lane * 8;
    float p = 0.f;
    #pragma unroll
    for (int j = 0; j < 8; ++j) {
      float v = arow[a0 + j] + att2_s[a0 + j];
      v = v > 0.f ? v : 0.f;
      p = fmaf(v, W_fa[a0 + j], p);
    }
    #pragma unroll
    for (int off = 32; off > 0; off >>= 1) p += __shfl_xor(p, off, 64);
    if (lane == 0) att_s[s] = p + b_fa[0];
  }
  __syncthreads();
  if (tid < 64) {
    float x = (tid < S_) ? att_s[tid] : -1e30f;
    float m = x;
    #pragma unroll
    for (int off = 32; off > 0; off >>= 1) m = fmaxf(m, __shfl_xor(m, off, 64));
    float e = (tid < S_) ? __expf(x - m) : 0.f;
    float su = e;
    #pragma unroll
    for (int off = 32; off > 0; off >>= 1) su += __shfl_xor(su, off, 64);
    if (tid < S_) alpha_s[tid] = e / su;
  }
  __syncthreads();
  if (tid < S_) {
    float old = scope[b * S_ + tid], al = alpha_s[tid];
    alphas_out[((size_t)b * T_ + t) * S_ + tid] = act ? old * al : 0.f;
    scope[b * S_ + tid] = act ? old * (1.f - al) : old;
  }
  for (int e = tid; e < D_; e += 256) {
    float aw = 0.f;
    for (int s = 0; s < S_; ++s)
      aw = fmaf(alpha_s[s], feats[((size_t)b * S_ + s) * D_ + e], aw);
    xg[b * D_ + e] = gate_s[e] * aw;
  }
}

// ---------------- S3: gi_awe matmul + GRU pointwise ----------------
// FIX R1: pin inner-loop unroll to 2. Compiler was fully unrolling the
// 32-trip kk loop (3 float4 streams -> ~96 in-flight loads), VGPR hit the
// 256 cap and spilled ~4KB/thread to scratch (85MB fetch + 135MB write per
// dispatch, 160us). #pragma unroll 2 keeps ~6 loads in flight.
__global__ __launch_bounds__(256) void k_S3(int t,
    float* __restrict__ h, const float* __restrict__ xg,
    const float* __restrict__ Yp, const float* __restrict__ gi_embed,
    const float* __restrict__ W_ih, const int* __restrict__ length,
    unsigned short* __restrict__ Hbuf) {
  __shared__ __align__(16) float xs[64 * 129];
  int tid = threadIdx.x;
  int b = tid & 63, jg = tid >> 6;
  int j = blockIdx.x * 4 + jg;
  const float* Wr = W_ih + (size_t)j * 1024 + 512;
  const float* Wz = W_ih + (size_t)(512 + j) * 1024 + 512;
  const float* Wn = W_ih + (size_t)(1024 + j) * 1024 + 512;
  float accr = 0.f, accz = 0.f, accn = 0.f;
  int lrow = tid >> 2, lkc = (tid & 3) * 32;
  for (int c = 0; c < 4; ++c) {
    int kb = c * 128;
    {
      const float* src = xg + lrow * 512 + kb + lkc;
      float* dst = xs + lrow * 129 + lkc;
      #pragma unroll
      for (int i = 0; i < 32; i += 4) {
        float4 v = *(const float4*)(src + i);
        dst[i] = v.x; dst[i + 1] = v.y; dst[i + 2] = v.z; dst[i + 3] = v.w;
      }
    }
    __syncthreads();
    const float* xrow = xs + b * 129;
    #pragma unroll 2
    for (int kk = 0; kk < 128; kk += 4) {
      float x0 = xrow[kk], x1 = xrow[kk + 1], x2 = xrow[kk + 2], x3 = xrow[kk + 3];
      float4 w;
      w = *(const float4*)(Wr + kb + kk);
      accr = fmaf(x0, w.x, fmaf(x1, w.y, fmaf(x2, w.z, fmaf(x3, w.w, accr))));
      w = *(const float4*)(Wz + kb + kk);
      accz = fmaf(x0, w.x, fmaf(x1, w.y, fmaf(x2, w.z, fmaf(x3, w.w, accz))));
      w = *(const float4*)(Wn + kb + kk);
      accn = fmaf(x0, w.x, fmaf(x1, w.y, fmaf(x2, w.z, fmaf(x3, w.w, accn))));
    }
    __syncthreads();
  }
  float ghr = 0.f, ghz = 0.f, ghn = 0.f;
  #pragma unroll
  for (int ks = 0; ks < 4; ++ks) {
    const float* y = Yp + ((size_t)ks * 64 + b) * NCAT;
    ghr += y[j]; ghz += y[512 + j]; ghn += y[1024 + j];
  }
  const float* gm = gi_embed + ((size_t)t * 64 + b) * G3;
  float r = sigm(accr + gm[j] + ghr);
  float z = sigm(accz + gm[512 + j] + ghz);
  float n = tanhf(accn + gm[1024 + j] + r * ghn);
  float hold = h[b * D_ + j];
  float hn = (1.f - z) * n + z * hold;
  bool act = t < length[b];
  h[b * D_ + j] = act ? hn : hold;
  Hbuf[((size_t)b * T_ + t) * D_ + j] = f2bf(hn);
}

// ---------------- Phase C: out = actmask * (Hbuf @ Wout.T + b_out) ----------------
// R1: 1D grid + chunked XCD swizzle (m-fast so each XCD's 500-block chunk
// reuses ~31 consecutive Wb n-panels from its own L2; Wb fetch 268MB->~40MB)
// + LDS chunk-XOR swizzle (c4 ^= (row>>1)&3) -> residual 2-way conflict (free).
__global__ __launch_bounds__(256) void k_outgemm(
    const unsigned short* __restrict__ Hb, const unsigned short* __restrict__ Wb,
    const float* __restrict__ b_out, const float* __restrict__ actmask,
    float* __restrict__ out) {
  __shared__ __align__(16) unsigned short As[128 * 32];
  __shared__ __align__(16) unsigned short Bs[128 * 32];
  // chunked XCD swizzle: 4000 blocks, 8 XCDs, 500 blocks/XCD chunk
  const int bid = blockIdx.x;
  const int swz = (bid & 7) * 500 + (bid >> 3);
  const int mb = (swz & 15) * 128;        // m fast
  const int nb = (swz >> 4) * 128;
  const int tid = threadIdx.x;
  const int l = tid & 63, w = tid >> 6;
  const int wr = w >> 1, wc = w & 1;
  const int lm = l & 15;
  const int kc = l >> 4;                  // k-chunk 0..3
  const int rchunk = (kc ^ ((lm >> 1) & 3)) * 8;  // swizzled read chunk offset
  v4f acc[4][4];
  #pragma unroll
  for (int mi = 0; mi < 4; ++mi)
    #pragma unroll
    for (int ni = 0; ni < 4; ++ni)
      acc[mi][ni] = (v4f){0.f, 0.f, 0.f, 0.f};

  for (int k0 = 0; k0 < 512; k0 += 32) {
    #pragma unroll
    for (int i = 0; i < 2; ++i) {
      int ch = i * 256 + tid;             // 0..511 16B-chunks
      int row = ch >> 2, c4 = ch & 3;
      int sc = (c4 ^ ((row >> 1) & 3)) * 8;
      *(int4*)&As[row * 32 + sc] =
          *(const int4*)&Hb[(size_t)(mb + row) * 512 + k0 + c4 * 8];
      *(int4*)&Bs[row * 32 + sc] =
          *(const int4*)&Wb[(size_t)(nb + row) * 512 + k0 + c4 * 8];
    }
    __syncthreads();
    s16x8 af[4], bf[4];
    #pragma unroll
    for (int mi = 0; mi < 4; ++mi)
      af[mi] = *(const s16x8*)&As[(wr * 64 + mi * 16 + lm) * 32 + rchunk];
    #pragma unroll
    for (int ni = 0; ni < 4; ++ni)
      bf[ni] = *(const s16x8*)&Bs[(wc * 64 + ni * 16 + lm) * 32 + rchunk];
    #pragma unroll
    for (int mi = 0; mi < 4; ++mi)
      #pragma unroll
      for (int ni = 0; ni < 4; ++ni)
        acc[mi][ni] = __builtin_amdgcn_mfma_f32_16x16x32_bf16(af[mi], bf[ni], acc[mi][ni], 0, 0, 0);
    __syncthreads();
  }
  #pragma unroll
  for (int ni = 0; ni < 4; ++ni) {
    int n = nb + wc * 64 + ni * 16 + lm;
    float bo = b_out[n];
    #pragma unroll
    for (int mi = 0; mi < 4; ++mi) {
      int m0 = mb + wr * 64 + mi * 16 + (l >> 4) * 4;
      #pragma unroll
      for (int r = 0; r < 4; ++r) {
        int m = m0 + r;
        out[(size_t)m * V_ + n] = actmask[m] * (acc[mi][ni][r] + bo);
      }
    }
  }
}

extern "C" void kernel_launch(void* const* d_in, const int* in_sizes, int n_in,
                              void* d_out, int out_size, void* d_ws, size_t ws_size,
                              hipStream_t stream) {
  const float* feats  = (const float*)d_in[0];
  const int*   seq    = (const int*)d_in[1];
  const int*   length = (const int*)d_in[2];
  const float* emb    = (const float*)d_in[3];
  const float* W_ih   = (const float*)d_in[4];
  const float* b_ih   = (const float*)d_in[5];
  const float* W_hh   = (const float*)d_in[6];
  const float* b_hh   = (const float*)d_in[7];
  const float* W_out  = (const float*)d_in[8];
  const float* b_out  = (const float*)d_in[9];
  const float* W_init = (const float*)d_in[10];
  const float* b_init = (const float*)d_in[11];
  const float* W_beta = (const float*)d_in[12];
  const float* b_beta = (const float*)d_in[13];
  const float* W_ea   = (const float*)d_in[14];
  const float* b_ea   = (const float*)d_in[15];
  const float* W_da   = (const float*)d_in[16];
  const float* b_da   = (const float*)d_in[17];
  const float* W_fa   = (const float*)d_in[18];
  const float* b_fa   = (const float*)d_in[19];

  float* out    = (float*)d_out;
  float* alphas = out + (size_t)B_ * T_ * V_;

  float* ws = (float*)d_ws;
  float* h        = ws; ws += B_ * D_;
  float* scope    = ws; ws += B_ * S_;
  float* hmean    = ws; ws += B_ * D_;
  float* xg       = ws; ws += B_ * D_;
  float* actmask  = ws; ws += B_ * T_;
  float* Yp       = ws; ws += 4 * B_ * NCAT;
  float* x_embed  = ws; ws += (size_t)B_ * T_ * D_;
  float* gi_embed = ws; ws += (size_t)B_ * T_ * G3;
  float* att1     = ws; ws += (size_t)B_ * S_ * D_;
  unsigned short* Hbuf  = (unsigned short*)ws;
  unsigned short* Woutb = Hbuf + (size_t)B_ * T_ * D_;

  // ---- Phase A: precompute (parallel) ----
  k_cvt<<<(V_ * D_) / 2048, 256, 0, stream>>>(W_out, Woutb);
  k_embed<<<B_ * T_, 128, 0, stream>>>(emb, seq, length, x_embed, actmask);
  k_hmean<<<B_, 256, 0, stream>>>(feats, hmean, scope);
  k_gemm_f32<<<dim3(8, 1), 256, 0, stream>>>(h, hmean, W_init, b_init, 512, 512, 512);
  k_gemm_f32<<<dim3(8, 49), 256, 0, stream>>>(att1, feats, W_ea, b_ea, 512, 512, 512);
  k_gemm_f32<<<dim3(24, 32), 256, 0, stream>>>(gi_embed, x_embed, W_ih, b_ih, 1536, 512, 1024);

  // ---- Phase B: recurrence ----
  for (int t = 0; t < T_; ++t) {
    k_S1<<<dim3(80, 4), 256, 0, stream>>>(h, W_hh, b_hh, W_da, b_da, W_beta, b_beta, Yp);
    k_S2<<<B_, 256, 0, stream>>>(t, Yp, att1, feats, W_fa, b_fa, length, scope, xg, alphas);
    k_S3<<<128, 256, 0, stream>>>(t, h, xg, Yp, gi_embed, W_ih, length, Hbuf);
  }

  // ---- Phase C: deferred output projection ----
  k_outgemm<<<4000, 256, 0, stream>>>(Hbuf, Woutb, b_out, actmask, out);
}